// Round 13
// baseline (239.302 us; speedup 1.0000x reference)
//
#include <hip/hip_runtime.h>
#include <math.h>

// ToneStack: 3 cascaded shelf biquads over x[64, 480000] fp32.
//
// R17 = R13 (proven session-best, ~80us dispatch) + bijective XCD swizzle.
//   Session ledger: R5 store-amp fix (137->92), R13 2-wave blocks
//   (85->80). Closed branches: load coalescing (R6/R11: costs residency,
//   net-negative), launch-bound occupancy forcing (R7/R9: spills at
//   cap<128), barrier elimination (R10: ~2us), Horner work cuts (R12:
//   not critical path), DMA pipelining (R14/R15: 2x correctness
//   failures), single-cohort/residency shaping (R16: REGRESSION 87us --
//   perfectly converged cohorts maximize phase collisions; R13's ragged
//   1.27 generations provide beneficial phase diversity).
//   R17's single variable: blockIdx swizzle wg=(bid%8)*(NBLK/8)+bid/8
//   (NBLK=4160%8==0 -> exactly bijective; indexing-only, same output
//   set). Consecutive logical blocks (same row, adjacent spans with
//   12-chunk overlapping history reads) land on one XCD's L2 ->
//   history re-reads (~13MB) become L2 hits + slight phase stagger.
//   Everything else is R13 verbatim: NT=128 (2 waves), HISTC=MTERM=12,
//   (128,4) bound, 2 barriers, wave-0 shuffle A-powers, wave-1 cn
//   table, superposition combine, per-wave 4KB store staging.

constexpr int T_LEN  = 480000;
constexpr int B_ROWS = 64;
constexpr int CHUNK  = 64;
constexpr int LOG2C  = 6;                     // A^64 = 6 squarings
constexpr int KCH    = T_LEN / CHUNK;         // 7500 chunks per row
constexpr int NT     = 128;                   // threads per block (2 waves)
constexpr int HISTC  = 12;                    // history chunks (768 samples)
constexpr int MTERM  = 12;                    // Horner terms (= horizon)
constexpr int OUTC   = NT - HISTC;            // 116 output chunks per block
constexpr int BLKROW = (KCH + OUTC - 1) / OUTC;  // 65 blocks per row
constexpr int NBLK   = B_ROWS * BLKROW;       // 4160 blocks (4160%8==0)
constexpr int NXCD   = 8;
constexpr int CPX    = NBLK / NXCD;           // 520 blocks per XCD chunk

struct Coeffs { float b0, b1, b2, a1, a2; };

__device__ __forceinline__ float rfl(float v) {
    return __int_as_float(__builtin_amdgcn_readfirstlane(__float_as_int(v)));
}

__device__ __forceinline__ Coeffs shelf(float fc, float gdb, float Q) {
    float A  = powf(10.0f, gdb * (1.0f / 40.0f));
    float w0 = 2.0f * 3.14159265358979323846f * fc / 48000.0f;
    float sw = sinf(w0), cw = cosf(w0);
    float alpha = sw / (2.0f * Q);
    float sqA = sqrtf(A);
    float b0 = A * ((A + 1.0f) - (A - 1.0f) * cw + 2.0f * sqA * alpha);
    float b1 = 2.0f * A * ((A - 1.0f) - (A + 1.0f) * cw);
    float b2 = A * ((A + 1.0f) - (A - 1.0f) * cw - 2.0f * sqA * alpha);
    float a0 = (A + 1.0f) + (A - 1.0f) * cw + 2.0f * sqA * alpha;
    float a1 = -2.0f * ((A - 1.0f) + (A + 1.0f) * cw);
    float a2 = (A + 1.0f) + (A - 1.0f) * cw - 2.0f * sqA * alpha;
    float rr = 1.0f / a0;
    Coeffs c;
    c.b0 = rfl(b0 * rr); c.b1 = rfl(b1 * rr); c.b2 = rfl(b2 * rr);
    c.a1 = rfl(a1 * rr); c.a2 = rfl(a2 * rr);
    return c;
}

// DF2T biquad step, op-for-op as reference:
//   y = b0*x + z1; z1' = b1*x - a1*y + z2; z2' = b2*x - a2*y
__device__ __forceinline__ float bq(float xn, const Coeffs& c, float& z1, float& z2) {
    float y = fmaf(c.b0, xn, z1);
    z1 = fmaf(-c.a1, y, fmaf(c.b1, xn, z2));
    z2 = fmaf(c.b2, xn, -(c.a2 * y));
    return y;
}

__device__ __forceinline__ float step6(float s[6], float x,
                                       const Coeffs& c1, const Coeffs& c2, const Coeffs& c3) {
    float y1 = bq(x,  c1, s[0], s[1]);
    float y2 = bq(y1, c2, s[2], s[3]);
    float y3 = bq(y2, c3, s[4], s[5]);
    return y3;
}

// y0 + cn[n].t6 (cn rows stride-8; broadcast LDS reads, const offsets)
__device__ __forceinline__ float corr(float y0, const float* cnp, const float t6[6]) {
    float4 ca = *(const float4*)(cnp);
    float2 cb = *(const float2*)(cnp + 4);
    float acc = fmaf(ca.x, t6[0], y0);
    acc = fmaf(ca.y, t6[1], acc);
    acc = fmaf(ca.z, t6[2], acc);
    acc = fmaf(ca.w, t6[3], acc);
    acc = fmaf(cb.x, t6[4], acc);
    acc = fmaf(cb.y, t6[5], acc);
    return acc;
}

__global__ __launch_bounds__(128, 4) void k_fused(
    const float* __restrict__ x,
    const float* __restrict__ p_lg, const float* __restrict__ p_mg,
    const float* __restrict__ p_mf, const float* __restrict__ p_mq,
    const float* __restrict__ p_hg,
    float* __restrict__ out)
{
    // smem: [0..896) doubles as the per-thread d store (dl, stride 7);
    // after barrier2 the 8KB is two per-wave 4KB store-staging quarters.
    __shared__ __align__(16) float smem[2048];
    __shared__ float M[36];                      // A^64
    __shared__ float Pw[LOG2C * 36];             // A^1,A^2,A^4,A^8,A^16,A^32
    __shared__ float Crow[8];                    // output row C of the cascade
    __shared__ __align__(16) float cn[64 * 8];   // C*A^n rows, stride 8

    const int t    = threadIdx.x;
    const int lane = t & 63;
    const int w    = t >> 6;
    // Bijective XCD swizzle (NBLK%8==0): consecutive logical blocks ->
    // same XCD chunk -> shared L2 for overlapping history reads.
    const int wg   = (blockIdx.x % NXCD) * CPX + blockIdx.x / NXCD;
    const int r = wg / BLKROW;
    const int b = wg - r * BLKROW;
    const int c = b * OUTC + t - HISTC;          // this thread's chunk index
    const int cbase = b * OUTC - HISTC;          // chunk index of thread 0
    const bool active = (c >= 0) && (c < KCH);

    Coeffs c1 = shelf(120.0f,  *p_lg, 0.707f);
    Coeffs c2 = shelf(*p_mf,   *p_mg, *p_mq);
    Coeffs c3 = shelf(4000.0f, *p_hg, 0.707f);

    // ---- load chunk into registers ----
    float4 xv[16];
    {
        int cc = c < 0 ? 0 : (c >= KCH ? KCH - 1 : c);
        const float4* lp = (const float4*)(x + (long long)r * T_LEN + (long long)cc * CHUNK);
        if (active) {
            #pragma unroll
            for (int q = 0; q < 16; ++q) xv[q] = lp[q];
        } else {
            #pragma unroll
            for (int q = 0; q < 16; ++q) xv[q] = make_float4(0.f, 0.f, 0.f, 0.f);
        }
    }

    // ---- wave 0: A columns + C row, then 6 shuffle-squarings, publish ----
    // Lane (i,j) = lane i*6+j holds A[i][j]; identical fma order to the
    // LDS version (acc=0; acc=fma(A[i][q],A[q][j],acc), q ascending).
    if (w == 0) {
        const int i  = lane / 6;                 // lanes >=36: clamped, unused
        const int j  = lane - 6 * i;
        const int i6 = i * 6;
        float e[6];
        #pragma unroll
        for (int jj = 0; jj < 6; ++jj) e[jj] = (jj == j) ? 1.0f : 0.0f;
        float y = step6(e, 0.0f, c1, c2, c3);    // e := A[:,j]; y = C[j]
        if (lane < 6) Crow[lane] = y;
        float aM = e[0];
        #pragma unroll
        for (int ii = 1; ii < 6; ++ii) aM = (i == ii) ? e[ii] : aM;
        for (int it = 0; it < LOG2C; ++it) {
            if (lane < 36) Pw[it * 36 + lane] = aM;   // snapshot A^(2^it)
            float acc = 0.f;
            #pragma unroll
            for (int q = 0; q < 6; ++q) {
                int sA = i6 + q; if (sA > 63) sA = 63;   // lanes >=36 only
                acc = fmaf(__shfl(aM, sA, 64), __shfl(aM, q * 6 + j, 64), acc);
            }
            aM = acc;
        }
        if (lane < 36) M[lane] = aM;             // A^64
    }

    // ---- pass 1: zero-state response, outputs written in place (y0) ----
    float s[6] = {0.f, 0.f, 0.f, 0.f, 0.f, 0.f};
    #pragma unroll
    for (int q = 0; q < 16; ++q) {
        float4 v = xv[q];
        v.x = step6(s, v.x, c1, c2, c3);
        v.y = step6(s, v.y, c1, c2, c3);
        v.z = step6(s, v.z, c1, c2, c3);
        v.w = step6(s, v.w, c1, c2, c3);
        xv[q] = v;
    }
    #pragma unroll
    for (int i = 0; i < 6; ++i) smem[t * 7 + i] = s[i];

    __syncthreads();                              // barrier1: dl + M + Pw + Crow

    float a[36];
    #pragma unroll
    for (int i = 0; i < 36; ++i) a[i] = rfl(M[i]);   // A^64 -> SGPRs

    // ---- cn rows on wave 1: cn[n] = C * prod_k A^(2^k * bit_k(n)) ----
    if (w == 1) {
        float row[6];
        #pragma unroll
        for (int jj = 0; jj < 6; ++jj) row[jj] = Crow[jj];
        #pragma unroll
        for (int k = 0; k < LOG2C; ++k) {
            if ((lane >> k) & 1) {
                const float* P = Pw + k * 36;
                float nr[6];
                #pragma unroll
                for (int jj = 0; jj < 6; ++jj) {
                    float acc = 0.f;
                    #pragma unroll
                    for (int q = 0; q < 6; ++q) acc = fmaf(row[q], P[q * 6 + jj], acc);
                    nr[jj] = acc;
                }
                #pragma unroll
                for (int jj = 0; jj < 6; ++jj) row[jj] = nr[jj];
            }
        }
        #pragma unroll
        for (int jj = 0; jj < 6; ++jj) cn[lane * 8 + jj] = row[jj];
    }

    // ---- truncated Horner scan over predecessors (oldest -> newest) ----
    float t6[6] = {0.f, 0.f, 0.f, 0.f, 0.f, 0.f};
    int m0 = t - MTERM; if (m0 < 0) m0 = 0;
    for (int m = m0; m < t; ++m) {
        float dm[6];
        #pragma unroll
        for (int i = 0; i < 6; ++i) dm[i] = smem[m * 7 + i];
        float nt6[6];
        #pragma unroll
        for (int i = 0; i < 6; ++i) {
            float acc = dm[i];
            #pragma unroll
            for (int j = 0; j < 6; ++j) acc = fmaf(a[i * 6 + j], t6[j], acc);
            nt6[i] = acc;
        }
        #pragma unroll
        for (int i = 0; i < 6; ++i) t6[i] = nt6[i];
    }

    __syncthreads();   // barrier2: cn ready; all dl reads done (smem reusable)

    // ---- combine: y[n] = y0[n] + cn[n].t6  (6 fma + 2 LDS bcast/sample) ----
    #pragma unroll
    for (int q = 0; q < 16; ++q) {
        float4 v = xv[q];
        v.x = corr(v.x, cn + (4 * q + 0) * 8, t6);
        v.y = corr(v.y, cn + (4 * q + 1) * 8, t6);
        v.z = corr(v.z, cn + (4 * q + 2) * 8, t6);
        v.w = corr(v.w, cn + (4 * q + 3) * 8, t6);
        xv[q] = v;
    }

    // ---- per-wave store staging, barrier-free (R5/R10 proven path) ----
    // Round j: source lanes 16j..16j+15 write their chunks (swizzled)
    // into this wave's quarter; all 64 lanes read back + store
    // 1KB-contiguous global. DS ops retire in-order per wave.
    float4* qv = ((float4*)smem) + w * 256;       // this wave's quarter
    float4* op = (float4*)(out + (long long)r * T_LEN);
    #pragma unroll
    for (int j = 0; j < 4; ++j) {
        if ((lane >> 4) == j) {
            const int sl  = lane & 15;
            const int key = sl & 7;
            #pragma unroll
            for (int q = 0; q < 16; ++q)
                qv[sl * 16 + (q ^ key)] = xv[q];
        }
        const long long base4 = (long long)(cbase + w * 64 + 16 * j) * 16;
        #pragma unroll
        for (int i = 0; i < 4; ++i) {
            const int sl = i * 4 + (lane >> 4);   // source slot in quarter
            const int qq = lane & 15;             // float4 within chunk
            const int tr = w * 64 + 16 * j + sl;  // owning thread index
            const int cc = cbase + tr;            // destination chunk
            if (tr >= HISTC && cc < KCH) {
                op[base4 + i * 64 + lane] = qv[sl * 16 + (qq ^ (sl & 7))];
            }
        }
    }
}

extern "C" void kernel_launch(void* const* d_in, const int* in_sizes, int n_in,
                              void* d_out, int out_size, void* d_ws, size_t ws_size,
                              hipStream_t stream) {
    const float* x  = (const float*)d_in[0];
    const float* lg = (const float*)d_in[1];
    const float* mg = (const float*)d_in[2];
    const float* mf = (const float*)d_in[3];
    const float* mq = (const float*)d_in[4];
    const float* hg = (const float*)d_in[5];
    float* out = (float*)d_out;

    hipLaunchKernelGGL(k_fused, dim3(NBLK), dim3(NT), 0, stream,
                       x, lg, mg, mf, mq, hg, out);
}

// Round 14
// 234.140 us; speedup vs baseline: 1.0220x; 1.0220x over previous
//
#include <hip/hip_runtime.h>
#include <math.h>

// ToneStack: 3 cascaded shelf biquads over x[64, 480000] fp32.
//
// R18 = R13 verbatim (restoration of the proven session-best: 80us
//   dispatch, 227us harness vs 251us baseline). R17's XCD swizzle cut
//   FETCH 9% (L2-locality mechanism confirmed) but cost +6-10us wall:
//   packing neighbor blocks onto one XCD concentrates phase-converged
//   load/store bursts onto the same L2/memory channels; default
//   round-robin channel balancing wins for this streaming op. Same
//   lesson as R16 (converged single cohort regressed): ANY increase in
//   spatial/temporal clustering of memory bursts loses; the ragged
//   spread-out default schedule is optimal for this latency-bound
//   streaming recurrence.
//   Full session ledger on this structure (all single-variable tested):
//   - write-amp fix via LDS store staging     R5   -45us  KEPT
//   - wave-coalesced load staging             R6/R11 costs residency  REJ
//   - occupancy forcing via launch bounds     R7/R9  spills (floor>102) REJ
//   - barrier elimination (22->2)             R10  ~2us   KEPT
//   - Horner work cut (issue not critical)    R12   0us   KEPT (MTERM=12)
//   - 2-wave blocks (phase diversity)         R13  -5us   KEPT
//   - DMA pipelining (counted vmcnt unsound
//     under divergent stores at HIP level)    R14/R15 2x correctness REJ
//   - exact single cohort                     R16  +7us   REJ
//   - XCD-locality swizzle                    R17  +6us   REJ
//   Remaining gap to the ~40us byte-floor is exposed latency in a
//   phase-bound streaming recurrence; no resource-neutral source-level
//   restructuring remains untested.

constexpr int T_LEN  = 480000;
constexpr int B_ROWS = 64;
constexpr int CHUNK  = 64;
constexpr int LOG2C  = 6;                     // A^64 = 6 squarings
constexpr int KCH    = T_LEN / CHUNK;         // 7500 chunks per row
constexpr int NT     = 128;                   // threads per block (2 waves)
constexpr int HISTC  = 12;                    // history chunks (768 samples)
constexpr int MTERM  = 12;                    // Horner terms (= horizon)
constexpr int OUTC   = NT - HISTC;            // 116 output chunks per block
constexpr int BLKROW = (KCH + OUTC - 1) / OUTC;  // 65 blocks per row
constexpr int NBLK   = B_ROWS * BLKROW;       // 4160 blocks

struct Coeffs { float b0, b1, b2, a1, a2; };

__device__ __forceinline__ float rfl(float v) {
    return __int_as_float(__builtin_amdgcn_readfirstlane(__float_as_int(v)));
}

__device__ __forceinline__ Coeffs shelf(float fc, float gdb, float Q) {
    float A  = powf(10.0f, gdb * (1.0f / 40.0f));
    float w0 = 2.0f * 3.14159265358979323846f * fc / 48000.0f;
    float sw = sinf(w0), cw = cosf(w0);
    float alpha = sw / (2.0f * Q);
    float sqA = sqrtf(A);
    float b0 = A * ((A + 1.0f) - (A - 1.0f) * cw + 2.0f * sqA * alpha);
    float b1 = 2.0f * A * ((A - 1.0f) - (A + 1.0f) * cw);
    float b2 = A * ((A + 1.0f) - (A - 1.0f) * cw - 2.0f * sqA * alpha);
    float a0 = (A + 1.0f) + (A - 1.0f) * cw + 2.0f * sqA * alpha;
    float a1 = -2.0f * ((A - 1.0f) + (A + 1.0f) * cw);
    float a2 = (A + 1.0f) + (A - 1.0f) * cw - 2.0f * sqA * alpha;
    float rr = 1.0f / a0;
    Coeffs c;
    c.b0 = rfl(b0 * rr); c.b1 = rfl(b1 * rr); c.b2 = rfl(b2 * rr);
    c.a1 = rfl(a1 * rr); c.a2 = rfl(a2 * rr);
    return c;
}

// DF2T biquad step, op-for-op as reference:
//   y = b0*x + z1; z1' = b1*x - a1*y + z2; z2' = b2*x - a2*y
__device__ __forceinline__ float bq(float xn, const Coeffs& c, float& z1, float& z2) {
    float y = fmaf(c.b0, xn, z1);
    z1 = fmaf(-c.a1, y, fmaf(c.b1, xn, z2));
    z2 = fmaf(c.b2, xn, -(c.a2 * y));
    return y;
}

__device__ __forceinline__ float step6(float s[6], float x,
                                       const Coeffs& c1, const Coeffs& c2, const Coeffs& c3) {
    float y1 = bq(x,  c1, s[0], s[1]);
    float y2 = bq(y1, c2, s[2], s[3]);
    float y3 = bq(y2, c3, s[4], s[5]);
    return y3;
}

// y0 + cn[n].t6 (cn rows stride-8; broadcast LDS reads, const offsets)
__device__ __forceinline__ float corr(float y0, const float* cnp, const float t6[6]) {
    float4 ca = *(const float4*)(cnp);
    float2 cb = *(const float2*)(cnp + 4);
    float acc = fmaf(ca.x, t6[0], y0);
    acc = fmaf(ca.y, t6[1], acc);
    acc = fmaf(ca.z, t6[2], acc);
    acc = fmaf(ca.w, t6[3], acc);
    acc = fmaf(cb.x, t6[4], acc);
    acc = fmaf(cb.y, t6[5], acc);
    return acc;
}

__global__ __launch_bounds__(128, 4) void k_fused(
    const float* __restrict__ x,
    const float* __restrict__ p_lg, const float* __restrict__ p_mg,
    const float* __restrict__ p_mf, const float* __restrict__ p_mq,
    const float* __restrict__ p_hg,
    float* __restrict__ out)
{
    // smem: [0..896) doubles as the per-thread d store (dl, stride 7);
    // after barrier2 the 8KB is two per-wave 4KB store-staging quarters.
    __shared__ __align__(16) float smem[2048];
    __shared__ float M[36];                      // A^64
    __shared__ float Pw[LOG2C * 36];             // A^1,A^2,A^4,A^8,A^16,A^32
    __shared__ float Crow[8];                    // output row C of the cascade
    __shared__ __align__(16) float cn[64 * 8];   // C*A^n rows, stride 8

    const int t    = threadIdx.x;
    const int lane = t & 63;
    const int w    = t >> 6;
    const int r = blockIdx.x / BLKROW;
    const int b = blockIdx.x - r * BLKROW;
    const int c = b * OUTC + t - HISTC;          // this thread's chunk index
    const int cbase = b * OUTC - HISTC;          // chunk index of thread 0
    const bool active = (c >= 0) && (c < KCH);

    Coeffs c1 = shelf(120.0f,  *p_lg, 0.707f);
    Coeffs c2 = shelf(*p_mf,   *p_mg, *p_mq);
    Coeffs c3 = shelf(4000.0f, *p_hg, 0.707f);

    // ---- load chunk into registers ----
    float4 xv[16];
    {
        int cc = c < 0 ? 0 : (c >= KCH ? KCH - 1 : c);
        const float4* lp = (const float4*)(x + (long long)r * T_LEN + (long long)cc * CHUNK);
        if (active) {
            #pragma unroll
            for (int q = 0; q < 16; ++q) xv[q] = lp[q];
        } else {
            #pragma unroll
            for (int q = 0; q < 16; ++q) xv[q] = make_float4(0.f, 0.f, 0.f, 0.f);
        }
    }

    // ---- wave 0: A columns + C row, then 6 shuffle-squarings, publish ----
    // Lane (i,j) = lane i*6+j holds A[i][j]; identical fma order to the
    // LDS version (acc=0; acc=fma(A[i][q],A[q][j],acc), q ascending).
    if (w == 0) {
        const int i  = lane / 6;                 // lanes >=36: clamped, unused
        const int j  = lane - 6 * i;
        const int i6 = i * 6;
        float e[6];
        #pragma unroll
        for (int jj = 0; jj < 6; ++jj) e[jj] = (jj == j) ? 1.0f : 0.0f;
        float y = step6(e, 0.0f, c1, c2, c3);    // e := A[:,j]; y = C[j]
        if (lane < 6) Crow[lane] = y;
        float aM = e[0];
        #pragma unroll
        for (int ii = 1; ii < 6; ++ii) aM = (i == ii) ? e[ii] : aM;
        for (int it = 0; it < LOG2C; ++it) {
            if (lane < 36) Pw[it * 36 + lane] = aM;   // snapshot A^(2^it)
            float acc = 0.f;
            #pragma unroll
            for (int q = 0; q < 6; ++q) {
                int sA = i6 + q; if (sA > 63) sA = 63;   // lanes >=36 only
                acc = fmaf(__shfl(aM, sA, 64), __shfl(aM, q * 6 + j, 64), acc);
            }
            aM = acc;
        }
        if (lane < 36) M[lane] = aM;             // A^64
    }

    // ---- pass 1: zero-state response, outputs written in place (y0) ----
    float s[6] = {0.f, 0.f, 0.f, 0.f, 0.f, 0.f};
    #pragma unroll
    for (int q = 0; q < 16; ++q) {
        float4 v = xv[q];
        v.x = step6(s, v.x, c1, c2, c3);
        v.y = step6(s, v.y, c1, c2, c3);
        v.z = step6(s, v.z, c1, c2, c3);
        v.w = step6(s, v.w, c1, c2, c3);
        xv[q] = v;
    }
    #pragma unroll
    for (int i = 0; i < 6; ++i) smem[t * 7 + i] = s[i];

    __syncthreads();                              // barrier1: dl + M + Pw + Crow

    float a[36];
    #pragma unroll
    for (int i = 0; i < 36; ++i) a[i] = rfl(M[i]);   // A^64 -> SGPRs

    // ---- cn rows on wave 1: cn[n] = C * prod_k A^(2^k * bit_k(n)) ----
    if (w == 1) {
        float row[6];
        #pragma unroll
        for (int jj = 0; jj < 6; ++jj) row[jj] = Crow[jj];
        #pragma unroll
        for (int k = 0; k < LOG2C; ++k) {
            if ((lane >> k) & 1) {
                const float* P = Pw + k * 36;
                float nr[6];
                #pragma unroll
                for (int jj = 0; jj < 6; ++jj) {
                    float acc = 0.f;
                    #pragma unroll
                    for (int q = 0; q < 6; ++q) acc = fmaf(row[q], P[q * 6 + jj], acc);
                    nr[jj] = acc;
                }
                #pragma unroll
                for (int jj = 0; jj < 6; ++jj) row[jj] = nr[jj];
            }
        }
        #pragma unroll
        for (int jj = 0; jj < 6; ++jj) cn[lane * 8 + jj] = row[jj];
    }

    // ---- truncated Horner scan over predecessors (oldest -> newest) ----
    float t6[6] = {0.f, 0.f, 0.f, 0.f, 0.f, 0.f};
    int m0 = t - MTERM; if (m0 < 0) m0 = 0;
    for (int m = m0; m < t; ++m) {
        float dm[6];
        #pragma unroll
        for (int i = 0; i < 6; ++i) dm[i] = smem[m * 7 + i];
        float nt6[6];
        #pragma unroll
        for (int i = 0; i < 6; ++i) {
            float acc = dm[i];
            #pragma unroll
            for (int j = 0; j < 6; ++j) acc = fmaf(a[i * 6 + j], t6[j], acc);
            nt6[i] = acc;
        }
        #pragma unroll
        for (int i = 0; i < 6; ++i) t6[i] = nt6[i];
    }

    __syncthreads();   // barrier2: cn ready; all dl reads done (smem reusable)

    // ---- combine: y[n] = y0[n] + cn[n].t6  (6 fma + 2 LDS bcast/sample) ----
    #pragma unroll
    for (int q = 0; q < 16; ++q) {
        float4 v = xv[q];
        v.x = corr(v.x, cn + (4 * q + 0) * 8, t6);
        v.y = corr(v.y, cn + (4 * q + 1) * 8, t6);
        v.z = corr(v.z, cn + (4 * q + 2) * 8, t6);
        v.w = corr(v.w, cn + (4 * q + 3) * 8, t6);
        xv[q] = v;
    }

    // ---- per-wave store staging, barrier-free (R5/R10 proven path) ----
    // Round j: source lanes 16j..16j+15 write their chunks (swizzled)
    // into this wave's quarter; all 64 lanes read back + store
    // 1KB-contiguous global. DS ops retire in-order per wave.
    float4* qv = ((float4*)smem) + w * 256;       // this wave's quarter
    float4* op = (float4*)(out + (long long)r * T_LEN);
    #pragma unroll
    for (int j = 0; j < 4; ++j) {
        if ((lane >> 4) == j) {
            const int sl  = lane & 15;
            const int key = sl & 7;
            #pragma unroll
            for (int q = 0; q < 16; ++q)
                qv[sl * 16 + (q ^ key)] = xv[q];
        }
        const long long base4 = (long long)(cbase + w * 64 + 16 * j) * 16;
        #pragma unroll
        for (int i = 0; i < 4; ++i) {
            const int sl = i * 4 + (lane >> 4);   // source slot in quarter
            const int qq = lane & 15;             // float4 within chunk
            const int tr = w * 64 + 16 * j + sl;  // owning thread index
            const int cc = cbase + tr;            // destination chunk
            if (tr >= HISTC && cc < KCH) {
                op[base4 + i * 64 + lane] = qv[sl * 16 + (qq ^ (sl & 7))];
            }
        }
    }
}

extern "C" void kernel_launch(void* const* d_in, const int* in_sizes, int n_in,
                              void* d_out, int out_size, void* d_ws, size_t ws_size,
                              hipStream_t stream) {
    const float* x  = (const float*)d_in[0];
    const float* lg = (const float*)d_in[1];
    const float* mg = (const float*)d_in[2];
    const float* mf = (const float*)d_in[3];
    const float* mq = (const float*)d_in[4];
    const float* hg = (const float*)d_in[5];
    float* out = (float*)d_out;

    hipLaunchKernelGGL(k_fused, dim3(NBLK), dim3(NT), 0, stream,
                       x, lg, mg, mf, mq, hg, out);
}